// Round 11
// baseline (171.106 us; speedup 1.0000x reference)
//
#include <hip/hip_runtime.h>
#include <hip/hip_bf16.h>

#define NROWS 65536
#define DIM   256
#define NCLS  1000
#define CPAD  1024

typedef __attribute__((ext_vector_type(8))) short bf16x8;   // 8 bf16 = 4 VGPR
typedef __attribute__((ext_vector_type(4))) float f32x4;    // MFMA C/D

// RTNE float -> bf16 bit pattern (finite inputs only)
__device__ inline unsigned short f2bf(float x) {
    unsigned int u = __builtin_bit_cast(unsigned int, x);
    unsigned int lsb = (u >> 16) & 1u;
    u += 0x7fffu + lsb;
    return (unsigned short)(u >> 16);
}

__device__ inline float bf2f(unsigned short u) {
    unsigned int v = ((unsigned int)u) << 16;
    return __builtin_bit_cast(float, v);
}

// async global->LDS, 16 B per lane, dst = wave-uniform base + lane*16
__device__ inline void gload_lds16(const void* g, void* l) {
    __builtin_amdgcn_global_load_lds(
        (const __attribute__((address_space(1))) unsigned int*)g,
        (__attribute__((address_space(3))) unsigned int*)l, 16, 0, 0);
}

// K1: fused gather + normalize. 2000 blocks = 1000 classes x 2 row-halves
// (~7.8 blocks/CU — the scan/gather is latency-bound and wants TLP, R9/R10).
// Ballot-scan half the labels; each matched row: load fp32 emb row (wave
// holds the full row), shuffle-reduce sumsq, normalize, accumulate fp32
// class sum, AND write the bf16 e row (each row matched exactly once ->
// e fully produced here; k_norm_acc is gone). Partial sums/counts written
// directly per (c,h) — no atomics, no zero-init. Block 0 zeroes acc/done.
__global__ __launch_bounds__(256) void k_gather_norm(
    const float* __restrict__ emb, const int* __restrict__ labels,
    unsigned short* __restrict__ e, float* __restrict__ sums_p,
    unsigned int* __restrict__ counts_p,
    float* __restrict__ acc, unsigned int* __restrict__ done)
{
    const int c   = blockIdx.x >> 1;       // 0..999
    const int h   = blockIdx.x & 1;        // row half
    const int tid = threadIdx.x;
    const int wave = tid >> 6, lane = tid & 63;
    if (blockIdx.x == 0 && tid == 0) { *acc = 0.0f; *done = 0u; }

    __shared__ float part[4][DIM];
    __shared__ unsigned int cnt_s[4];

    const int base = h * (NROWS / 2);
    float a0 = 0.f, a1 = 0.f, a2 = 0.f, a3 = 0.f;
    unsigned int cnt = 0;

    for (int it = 0; it < (NROWS / 2) / 256 / 8; ++it) {   // 16 iterations
        int lb[8];
        #pragma unroll
        for (int u = 0; u < 8; ++u)
            lb[u] = labels[base + (it * 8 + u) * 256 + wave * 64 + lane];
        #pragma unroll
        for (int u = 0; u < 8; ++u) {
            unsigned long long m = __ballot(lb[u] == c);
            cnt += (unsigned int)__popcll(m);
            int rb = base + (it * 8 + u) * 256 + wave * 64;
            while (m) {                    // wave-uniform loop (m from ballot)
                int b = __ffsll((long long)m) - 1;  m &= m - 1;
                int r = rb + b;
                float4 v = ((const float4*)(emb + (size_t)r * DIM))[lane];
                float ss = v.x*v.x + v.y*v.y + v.z*v.z + v.w*v.w;
                #pragma unroll
                for (int off = 1; off < 64; off <<= 1) ss += __shfl_xor(ss, off);
                float inv = 1.0f / fmaxf(sqrtf(ss), 1e-12f);
                v.x *= inv; v.y *= inv; v.z *= inv; v.w *= inv;
                ushort4 u16;
                u16.x = f2bf(v.x); u16.y = f2bf(v.y);
                u16.z = f2bf(v.z); u16.w = f2bf(v.w);
                ((ushort4*)(e + (size_t)r * DIM))[lane] = u16;   // produce e
                a0 += v.x; a1 += v.y; a2 += v.z; a3 += v.w;
            }
        }
    }
    ((float4*)part[wave])[lane] = make_float4(a0, a1, a2, a3);
    if (lane == 0) cnt_s[wave] = cnt;
    __syncthreads();

    float s = part[0][tid] + part[1][tid] + part[2][tid] + part[3][tid];
    sums_p[((size_t)h * CPAD + c) * DIM + tid] = s;          // direct write
    if (tid == 0)
        counts_p[h * CPAD + c] = cnt_s[0] + cnt_s[1] + cnt_s[2] + cnt_s[3];
}

// K2: one wave per class (all CPAD): combine 2 partials, center =
// sum/max(cnt,1), fold 1/max(||c||,1e-8), store bf16. Phantoms (c>=NCLS,
// partials unwritten) -> explicit zeros.
__global__ __launch_bounds__(256) void k_centers(
    const float* __restrict__ sums_p, const unsigned int* __restrict__ counts_p,
    unsigned short* __restrict__ cs)
{
    int gid  = blockIdx.x * 256 + threadIdx.x;
    int c    = gid >> 6;          // wave-uniform
    int lane = gid & 63;
    float4 v = make_float4(0.f, 0.f, 0.f, 0.f);
    if (c < NCLS) {
        float4 v0 = ((const float4*)(sums_p + ((size_t)0 * CPAD + c) * DIM))[lane];
        float4 v1 = ((const float4*)(sums_p + ((size_t)1 * CPAD + c) * DIM))[lane];
        v.x = v0.x + v1.x; v.y = v0.y + v1.y;
        v.z = v0.z + v1.z; v.w = v0.w + v1.w;
        float ic = 1.0f / fmaxf((float)(counts_p[c] + counts_p[CPAD + c]), 1.0f);
        v.x *= ic; v.y *= ic; v.z *= ic; v.w *= ic;
        float ss = v.x*v.x + v.y*v.y + v.z*v.z + v.w*v.w;
        #pragma unroll
        for (int off = 1; off < 64; off <<= 1) ss += __shfl_xor(ss, off);
        float sc = 1.0f / fmaxf(sqrtf(ss), 1e-8f);
        v.x *= sc; v.y *= sc; v.z *= sc; v.w *= sc;
    }
    ushort4 u;
    u.x = f2bf(v.x); u.y = f2bf(v.y); u.z = f2bf(v.z); u.w = f2bf(v.w);
    ((ushort4*)(cs + (size_t)c * DIM))[lane] = u;
}

// K3: bf16 MFMA GEMM-BT + fused loss + fused finalization (R8, unchanged).
// A kc=0,1 in LDS (32 KB); A kc=2,3 in 64 VGPRs, ALL indices compile-time
// (runtime-indexed reg arrays spill to scratch — R7 lesson). B glds
// double-buffered; one barrier per step. LDS 64 KB -> 2 blocks/CU.
#define TMB 128
#define TCB 128

__global__ __launch_bounds__(256, 2) void k_loss_mfma(
    const unsigned short* __restrict__ e, const unsigned short* __restrict__ cs,
    const int* __restrict__ labels, float* __restrict__ acc,
    unsigned int* __restrict__ done, float* __restrict__ out)
{
    __shared__ __align__(16) unsigned short a_s[2][TMB * 64];  // 32 KB
    __shared__ __align__(16) unsigned short b_s[2][TCB * 64];  // 32 KB
    __shared__ float red_s[4];

    const int tid  = threadIdx.x;
    const int row0 = blockIdx.x * TMB;
    const int wave = tid >> 6, lane = tid & 63;
    const int wm = wave >> 1, wn = wave & 1;   // 2x2 wave grid, 64x64 tiles
    const int l16 = lane & 15, q = lane >> 4;
    const int st_r = lane >> 3;                // staging row within 8-row chunk
    const int st_s = (lane & 7) ^ st_r;        // XOR-swizzled source slice

    int labv[16];
    #pragma unroll
    for (int mi = 0; mi < 4; ++mi)
        #pragma unroll
        for (int rg = 0; rg < 4; ++rg)
            labv[mi * 4 + rg] = labels[row0 + wm*64 + mi*16 + q*4 + rg];

    // stage A kc=0,1 into LDS (8 glds/wave)
    #pragma unroll
    for (int kc = 0; kc < 2; ++kc)
        #pragma unroll
        for (int ch = 0; ch < 4; ++ch) {
            int chunk = wave * 4 + ch;
            int row   = chunk * 8 + st_r;
            gload_lds16(&e[(size_t)(row0 + row) * DIM + kc * 64 + st_s * 8],
                        &a_s[kc][chunk * 512]);
        }
    // A kc=2,3 into registers (plain loads; indices all compile-time)
    bf16x8 af2[4][2], af3[4][2];
    #pragma unroll
    for (int mi = 0; mi < 4; ++mi) {
        const unsigned short* pa =
            e + (size_t)(row0 + wm*64 + mi*16 + l16) * DIM + 128 + q * 8;
        af2[mi][0] = *(const bf16x8*)pa;
        af2[mi][1] = *(const bf16x8*)(pa + 32);
        af3[mi][0] = *(const bf16x8*)(pa + 64);
        af3[mi][1] = *(const bf16x8*)(pa + 96);
    }
    // stage B step 0
    #pragma unroll
    for (int ch = 0; ch < 4; ++ch) {
        int chunk = wave * 4 + ch;
        int row   = chunk * 8 + st_r;
        gload_lds16(&cs[(size_t)row * DIM + st_s * 8], &b_s[0][chunk * 512]);
    }
    __syncthreads();   // drains all preamble glds; A + B(0) visible

    float la_bulk = 0.0f, la_corr = 0.0f;
    const float KN = 1.0f / 999.0f;

    for (int cb = 0; cb < CPAD / TCB; ++cb) {
        f32x4 accf[4][4];
        #pragma unroll
        for (int mi = 0; mi < 4; ++mi)
            #pragma unroll
            for (int ni = 0; ni < 4; ++ni)
                accf[mi][ni] = (f32x4){0.f, 0.f, 0.f, 0.f};

        #pragma unroll
        for (int kc = 0; kc < 4; ++kc) {
            // prefetch next step into buffer (kc+1)&1 (compile-time parity)
            if (cb < 7 || kc < 3) {
                const int cb2 = (kc == 3) ? cb + 1 : cb;
                const int kc2 = (kc + 1) & 3;
                #pragma unroll
                for (int ch = 0; ch < 4; ++ch) {
                    int chunk = wave * 4 + ch;
                    int row   = chunk * 8 + st_r;
                    gload_lds16(&cs[(size_t)(cb2 * TCB + row) * DIM + kc2 * 64 + st_s * 8],
                                &b_s[(kc + 1) & 1][chunk * 512]);
                }
            }
            const unsigned short* bs = b_s[kc & 1];
            #pragma unroll
            for (int kk = 0; kk < 2; ++kk) {
                bf16x8 af[4], bfr[4];
                #pragma unroll
                for (int mi = 0; mi < 4; ++mi) {
                    if (kc == 0 || kc == 1) {
                        int rowA = wm*64 + mi*16 + l16;
                        af[mi] = *(const bf16x8*)&a_s[kc][
                            rowA*64 + (((kk*4 + q) ^ (rowA & 7)) * 8)];
                    } else if (kc == 2) {
                        af[mi] = af2[mi][kk];
                    } else {
                        af[mi] = af3[mi][kk];
                    }
                }
                #pragma unroll
                for (int ni = 0; ni < 4; ++ni) {
                    int rowB = wn*64 + ni*16 + l16;
                    bfr[ni] = *(const bf16x8*)&bs[rowB*64 + (((kk*4 + q) ^ (rowB & 7)) * 8)];
                }
                #pragma unroll
                for (int mi = 0; mi < 4; ++mi)
                    #pragma unroll
                    for (int ni = 0; ni < 4; ++ni)
                        accf[mi][ni] = __builtin_amdgcn_mfma_f32_16x16x32_bf16(
                            af[mi], bfr[ni], accf[mi][ni], 0, 0, 0);
            }
            __syncthreads();   // readers of b_s[kc&1] done; covers prefetch
        }

        // epilogue for this class tile: C/D col = l16, row = q*4 + reg
        #pragma unroll
        for (int mi = 0; mi < 4; ++mi)
            #pragma unroll
            for (int rg = 0; rg < 4; ++rg) {
                #pragma unroll
                for (int ni = 0; ni < 4; ++ni) {
                    float t = 1.0f - accf[mi][ni][rg];
                    la_bulk += t * t;
                }
                int lr = labv[mi*4 + rg] - cb*128 - wn*64 - l16;
                if ((lr & ~48) == 0) {
                    int nih = lr >> 4;
                    float sv = (nih == 0) ? accf[mi][0][rg] :
                               (nih == 1) ? accf[mi][1][rg] :
                               (nih == 2) ? accf[mi][2][rg] : accf[mi][3][rg];
                    float t = 1.0f - sv;
                    la_corr += t * t;
                }
            }
    }

    // block reduction + fused finalization via atomic ticket
    float la = la_bulk * KN + la_corr * (1.0f - KN);
    #pragma unroll
    for (int off = 32; off >= 1; off >>= 1) la += __shfl_xor(la, off);
    if (lane == 0) red_s[wave] = la;
    __syncthreads();
    if (tid == 0) {
        atomicAdd(acc, red_s[0] + red_s[1] + red_s[2] + red_s[3]);
        __threadfence();
        unsigned int t = atomicAdd(done, 1u);
        if (t == (unsigned int)(NROWS / TMB) - 1u) {
            float v = atomicAdd(acc, 0.0f);    // atomic read: all adds visible
            out[0] = v * (1.0f / (float)NROWS) - 24.0f * (1.0f / 999.0f);
        }
    }
}

extern "C" void kernel_launch(void* const* d_in, const int* in_sizes, int n_in,
                              void* d_out, int out_size, void* d_ws, size_t ws_size,
                              hipStream_t stream)
{
    const float* emb    = (const float*)d_in[0];
    const int*   labels = (const int*)d_in[1];
    float*       out    = (float*)d_out;
    char*        ws     = (char*)d_ws;

    const size_t OFF_CS   = (size_t)NROWS * DIM * 2;             // e: 32 MB
    const size_t OFF_SUMS = OFF_CS + (size_t)CPAD * DIM * 2;     // cs: 512 KB
    const size_t OFF_CNT  = OFF_SUMS + (size_t)2 * CPAD * DIM * 4; // sums_p: 2 MB
    const size_t OFF_ACC  = OFF_CNT + (size_t)2 * CPAD * 4;      // counts_p: 8 KB
    const size_t OFF_DONE = OFF_ACC + 16;

    unsigned short* e        = (unsigned short*)ws;
    unsigned short* cs       = (unsigned short*)(ws + OFF_CS);
    float*          sums_p   = (float*)(ws + OFF_SUMS);
    unsigned int*   counts_p = (unsigned int*)(ws + OFF_CNT);
    float*          acc      = (float*)(ws + OFF_ACC);
    unsigned int*   done     = (unsigned int*)(ws + OFF_DONE);

    k_gather_norm<<<NCLS * 2, 256, 0, stream>>>(emb, labels, e, sums_p,
                                                counts_p, acc, done);
    k_centers    <<<CPAD / 4, 256, 0, stream>>>(sums_p, counts_p, cs);
    k_loss_mfma  <<<NROWS / TMB, 256, 0, stream>>>(e, cs, labels, acc, done, out);
}